// Round 18
// baseline (63.088 us; speedup 1.0000x reference)
//
#include <hip/hip_runtime.h>
#include <hip/hip_bf16.h>

// EdgeLearnGNN: B=16, N=64, F=1024, K=13, C=2
// Round 17: push the proven occupancy lever (r17: 128x64 tiles -> -3.2us) one
// notch: GEMM tile 64x64, 512 GEMM blocks + 256 spart = 768 total. LDS 18.4KB ->
// 3+ blocks/CU resident; per-block MFMA chain halves (64 MFMA). gpart layout,
// K-slice count (2), per-output accumulation order, spart/k2/k3: byte-identical
// to r17 (risk containment after r15's unexplained failure). XCD regions: each
// XCD owns 4 M-tiles x 8 N-tiles, A 1MB + B 2MB, both slices, L2-resident.
//   K1: 768 blocks: 512 GEMM g=x@W^T (64x64 x K512, XCD-local) | 256 spart+warm
//   K2: 256 blocks (b,ft): adj recompute + h2=(A+I)@g+gin_b + BN1 partials
//   K3: 64 blocks: BN1 reduce + folded mix + conv13 + BN2 part + [mod-ticket: head]

typedef __attribute__((ext_vector_type(8))) __bf16 bf16x8;
typedef __attribute__((ext_vector_type(4))) float f32x4;

__device__ __forceinline__ unsigned short f2bf(float f) {
  union { float f; unsigned int u; } v; v.f = f;
  unsigned int r = v.u + 0x7FFFu + ((v.u >> 16) & 1u);   // RNE, finite values only
  return (unsigned short)(r >> 16);
}

// ---------------- K1: XCD-local GEMM (bid<512) + spart tiles (bid>=512) ----------------
__global__ __launch_bounds__(256) void k1_spart_gemm(
    const float* __restrict__ x, const float* __restrict__ w,
    const float* __restrict__ gin_W,
    float* __restrict__ spart, float* __restrict__ gpart) {
  __shared__ __align__(16) union {
    struct { float xt[64 * 68]; float wt[64]; } s;
    struct { unsigned short A[64 * 72]; unsigned short B[64 * 72]; } g;   // 18.4 KB
  } sm;
  int t = threadIdx.x, bid = blockIdx.x;

  if (bid >= 512) {
    // ----- pairwise weighted-L1 partial scores, tile (b, ft) + gin_W warm -----
    int sbid = bid - 512;
    int b = sbid >> 4, ft = sbid & 15, f0 = ft * 64;
    // issue gin_W touch-loads FIRST (this block's 16KB slice; 256 blocks = 4MB);
    // consumed only by the asm keep below -> retire whenever, warm L3/L2.
    const float4* pf = reinterpret_cast<const float4*>(gin_W) + (size_t)sbid * 1024 + t;
    float4 pf0 = pf[0], pf1 = pf[256], pf2 = pf[512], pf3 = pf[768];
    for (int c = 0; c < 16; ++c) {
      int idx = c * 256 + t;
      int n = idx >> 6, f = idx & 63;
      sm.s.xt[n * 68 + f] = x[b * 65536 + n * 1024 + f0 + f];
    }
    if (t < 64) sm.s.wt[t] = w[f0 + t];
    __syncthreads();
    asm volatile("" :: "v"(pf0.x), "v"(pf1.x), "v"(pf2.x), "v"(pf3.x));  // keep loads live
    int i0 = (t >> 4) * 4, j0 = (t & 15) * 4;
    float acc[4][4];
#pragma unroll
    for (int ii = 0; ii < 4; ++ii)
#pragma unroll
      for (int jj = 0; jj < 4; ++jj) acc[ii][jj] = 0.f;
    for (int f = 0; f < 64; f += 4) {
      float4 wv = *reinterpret_cast<const float4*>(&sm.s.wt[f]);
      float4 av[4], bv[4];
#pragma unroll
      for (int ii = 0; ii < 4; ++ii) av[ii] = *reinterpret_cast<const float4*>(&sm.s.xt[(i0 + ii) * 68 + f]);
#pragma unroll
      for (int jj = 0; jj < 4; ++jj) bv[jj] = *reinterpret_cast<const float4*>(&sm.s.xt[(j0 + jj) * 68 + f]);
#pragma unroll
      for (int ii = 0; ii < 4; ++ii)
#pragma unroll
        for (int jj = 0; jj < 4; ++jj) {
          acc[ii][jj] += fabsf(av[ii].x - bv[jj].x) * wv.x
                       + fabsf(av[ii].y - bv[jj].y) * wv.y
                       + fabsf(av[ii].z - bv[jj].z) * wv.z
                       + fabsf(av[ii].w - bv[jj].w) * wv.w;
        }
    }
    float* out = spart + (size_t)sbid * 4096;
#pragma unroll
    for (int ii = 0; ii < 4; ++ii)
#pragma unroll
      for (int jj = 0; jj < 4; ++jj)
        out[(i0 + ii) * 64 + (j0 + jj)] = acc[ii][jj];
    return;
  }

  // ----- GEMM g = x @ W^T: 512 blocks, tile 64x64, K-slice 512, XCD regions -----
  // g in 0..511: xcd = g&7; idx = g>>3 in 0..63: lt = idx&31 (tile in region),
  // slice = idx>>5 (0..1). Region: 4 M-tiles x 8 N-tiles per XCD ->
  // A 1MB + B 2MB footprint, both slices co-located, L2-resident.
  int g = bid;
  int xcd = g & 7, idx = g >> 3;
  int lt = idx & 31, slice = idx >> 5;
  int tr = 4 * (xcd & 3) + (lt >> 3);      // 0..15 (M-tile of 64 rows)
  int tc = 8 * (xcd >> 2) + (lt & 7);      // 0..15 (N-tile of 64 cols)
  int k0 = slice * 512;
  int wave = t >> 6, lane = t & 63;
  int wr = wave * 16;                      // wave: 16 rows x 64 cols
  int lrow = lane & 15, kg = lane >> 4;
  f32x4 acc[4];
#pragma unroll
  for (int nj = 0; nj < 4; ++nj) acc[nj] = f32x4{0.f, 0.f, 0.f, 0.f};

  for (int chunk = 0; chunk < 8; ++chunk) {
    int kc = k0 + chunk * 64;
#pragma unroll
    for (int u = 0; u < 4; ++u) {            // A: 64 rows x 64 k
      int idx4 = u * 256 + t;
      int row = idx4 >> 4, kq = idx4 & 15;
      float4 va = *reinterpret_cast<const float4*>(&x[(size_t)(tr * 64 + row) * 1024 + kc + kq * 4]);
      ushort4 ua; ua.x = f2bf(va.x); ua.y = f2bf(va.y); ua.z = f2bf(va.z); ua.w = f2bf(va.w);
      *reinterpret_cast<ushort4*>(&sm.g.A[row * 72 + kq * 4]) = ua;
    }
#pragma unroll
    for (int u = 0; u < 4; ++u) {            // B: 64 rows x 64 k
      int idx4 = u * 256 + t;
      int row = idx4 >> 4, kq = idx4 & 15;
      float4 vb = *reinterpret_cast<const float4*>(&gin_W[(size_t)(tc * 64 + row) * 1024 + kc + kq * 4]);
      ushort4 ub; ub.x = f2bf(vb.x); ub.y = f2bf(vb.y); ub.z = f2bf(vb.z); ub.w = f2bf(vb.w);
      *reinterpret_cast<ushort4*>(&sm.g.B[row * 72 + kq * 4]) = ub;
    }
    __syncthreads();
#pragma unroll
    for (int ks = 0; ks < 2; ++ks) {
      bf16x8 a = *reinterpret_cast<const bf16x8*>(&sm.g.A[(wr + lrow) * 72 + ks * 32 + kg * 8]);
      bf16x8 bf_[4];
#pragma unroll
      for (int nj = 0; nj < 4; ++nj)
        bf_[nj] = *reinterpret_cast<const bf16x8*>(&sm.g.B[(nj * 16 + lrow) * 72 + ks * 32 + kg * 8]);
#pragma unroll
      for (int nj = 0; nj < 4; ++nj)
        acc[nj] = __builtin_amdgcn_mfma_f32_16x16x32_bf16(a, bf_[nj], acc[nj], 0, 0, 0);
    }
    __syncthreads();
  }
  float* gp = gpart + (size_t)slice * (1024u * 1024u);
#pragma unroll
  for (int nj = 0; nj < 4; ++nj) {
    int row = tr * 64 + wr + kg * 4;              // C/D: row = (lane>>4)*4 + reg
    int col = tc * 64 + nj * 16 + lrow;           // col = lane&15
#pragma unroll
    for (int r = 0; r < 4; ++r)
      gp[(size_t)(row + r) * 1024 + col] = acc[nj][r];
  }
}

// ---- K2: adj[b] recompute + h2 = (A+I)@g + gin_b + BN1 partials. ----
// XCD-swizzled: the 16 blocks of batch b share one XCD -> spart[b]+g[b] L2-hit.
// adj phase float4-vectorized: thread owns rows tr4*4..+3 x cols tj*4..+3.
__global__ __launch_bounds__(256) void k2_adj_h2(
    const float* __restrict__ spart, const float* __restrict__ gpart,
    const float* __restrict__ gin_b,
    float* __restrict__ dout, float* __restrict__ h2, float* __restrict__ part) {
  __shared__ float adjs[64 * 65];
  __shared__ float csum[16][64];
  __shared__ float cinv[64];
  __shared__ __align__(16) float gt[64 * 68];
  int t = threadIdx.x, bid = blockIdx.x;
  int xcd = bid & 7, local = bid >> 3;
  int b = (xcd << 1) | (local & 1);
  int ft = local >> 1;
  int f0 = ft * 64;
  // g tile: sum the 2 K-slice partials -> gt[64][68]
  {
    int i = t >> 4, fl = (t & 15) * 4;
#pragma unroll
    for (int c = 0; c < 4; ++c) {
      int row = c * 16 + i;
      const float* base = gpart + (size_t)(b * 64 + row) * 1024 + f0 + fl;
      float4 s0 = *reinterpret_cast<const float4*>(base);
      float4 s1 = *reinterpret_cast<const float4*>(base + (1u << 20));
      float4 g4;
      g4.x = s0.x + s1.x; g4.y = s0.y + s1.y;
      g4.z = s0.z + s1.z; g4.w = s0.w + s1.w;
      *reinterpret_cast<float4*>(&gt[row * 68 + fl]) = g4;
    }
  }
  // adj[b] from spart, float4 over columns (redundant per ft; ft==0 writes dout)
  int tj = t & 15, tr4 = t >> 4;              // cols tj*4..+3, rows tr4*4..+3
  float4 v4[4];
#pragma unroll
  for (int r = 0; r < 4; ++r) v4[r] = make_float4(0.f, 0.f, 0.f, 0.f);
  for (int ft2 = 0; ft2 < 16; ++ft2) {
    const float* p = spart + (size_t)(b * 16 + ft2) * 4096 + tj * 4;
#pragma unroll
    for (int r = 0; r < 4; ++r) {
      float4 s = *reinterpret_cast<const float4*>(&p[(tr4 * 4 + r) * 64]);
      v4[r].x += s.x; v4[r].y += s.y; v4[r].z += s.z; v4[r].w += s.w;
    }
  }
  float4 colsum = make_float4(0.f, 0.f, 0.f, 0.f);
#pragma unroll
  for (int r = 0; r < 4; ++r) {
    float4 e;
    e.x = expf(-fmaxf(v4[r].x, 0.f));
    e.y = expf(-fmaxf(v4[r].y, 0.f));
    e.z = expf(-fmaxf(v4[r].z, 0.f));
    e.w = expf(-fmaxf(v4[r].w, 0.f));
    int row = tr4 * 4 + r;
    adjs[row * 65 + tj * 4 + 0] = e.x;
    adjs[row * 65 + tj * 4 + 1] = e.y;
    adjs[row * 65 + tj * 4 + 2] = e.z;
    adjs[row * 65 + tj * 4 + 3] = e.w;
    colsum.x += e.x; colsum.y += e.y; colsum.z += e.z; colsum.w += e.w;
  }
  csum[tr4][tj * 4 + 0] = colsum.x;
  csum[tr4][tj * 4 + 1] = colsum.y;
  csum[tr4][tj * 4 + 2] = colsum.z;
  csum[tr4][tj * 4 + 3] = colsum.w;
  __syncthreads();
  if (t < 64) {
    float s = 0.f;
#pragma unroll
    for (int g2 = 0; g2 < 16; ++g2) s += csum[g2][t];
    cinv[t] = 1.f / s;
  }
  __syncthreads();
  float* doutAdj = dout + 32 + (size_t)b * 4096;
#pragma unroll
  for (int r = 0; r < 4; ++r) {
    int row = tr4 * 4 + r;
#pragma unroll
    for (int c = 0; c < 4; ++c) {
      int col = tj * 4 + c;
      float a = adjs[row * 65 + col] * cinv[col];
      adjs[row * 65 + col] = a;
      if (ft == 0) doutAdj[row * 64 + col] = a;
    }
  }
  __syncthreads();
  // h2 tile = gt (identity) + adj@gt + gin_b; BN1 partials over the tile's 64 cols
  int i0 = (t >> 4) * 4, fl = (t & 15) * 4;
  float4 gbv = *reinterpret_cast<const float4*>(&gin_b[f0 + fl]);
  float4 acc4[4];
#pragma unroll
  for (int ii = 0; ii < 4; ++ii)
    acc4[ii] = *reinterpret_cast<const float4*>(&gt[(i0 + ii) * 68 + fl]);  // identity
  for (int j = 0; j < 64; ++j) {
    float4 gv = *reinterpret_cast<const float4*>(&gt[j * 68 + fl]);
#pragma unroll
    for (int ii = 0; ii < 4; ++ii) {
      float a = adjs[(i0 + ii) * 65 + j];
      acc4[ii].x += a * gv.x; acc4[ii].y += a * gv.y;
      acc4[ii].z += a * gv.z; acc4[ii].w += a * gv.w;
    }
  }
  float rs[4], rq[4];
#pragma unroll
  for (int ii = 0; ii < 4; ++ii) {
    acc4[ii].x += gbv.x; acc4[ii].y += gbv.y; acc4[ii].z += gbv.z; acc4[ii].w += gbv.w;
    *reinterpret_cast<float4*>(&h2[(size_t)(b * 64 + i0 + ii) * 1024 + f0 + fl]) = acc4[ii];
    rs[ii] = (acc4[ii].x + acc4[ii].y) + (acc4[ii].z + acc4[ii].w);
    rq[ii] = (acc4[ii].x * acc4[ii].x + acc4[ii].y * acc4[ii].y)
           + (acc4[ii].z * acc4[ii].z + acc4[ii].w * acc4[ii].w);
  }
#pragma unroll
  for (int m = 1; m < 16; m <<= 1) {
#pragma unroll
    for (int r = 0; r < 4; ++r) {
      rs[r] += __shfl_xor(rs[r], m, 64);
      rq[r] += __shfl_xor(rq[r], m, 64);
    }
  }
  if ((t & 15) == 0) {
    float* pp = part + (size_t)(b * 16 + ft) * 128;
#pragma unroll
    for (int r = 0; r < 4; ++r) {
      int n = i0 + r;
      pp[2 * n]     = rs[r];
      pp[2 * n + 1] = rq[r];
    }
  }
}

// ---- K3: 64 blocks (b, 256-f quarter). BN1 reduce + folded mix + conv13 +
//      BN2 partials; modulo terminal ticket -> unique residue-63 block runs the head. ----
__global__ __launch_bounds__(256) void k3_y_head(
    const float* __restrict__ h2, const float* __restrict__ part,
    const float* __restrict__ lc_W, const float* __restrict__ lc_b,
    const float* __restrict__ bn1_g, const float* __restrict__ bn1_b,
    const float* __restrict__ conv_W, const float* __restrict__ conv_b,
    const float* __restrict__ bn2_g, const float* __restrict__ bn2_b,
    const float* __restrict__ out_W, const float* __restrict__ out_b,
    float* __restrict__ y2, float* __restrict__ bn2part,
    float* __restrict__ dout, unsigned* __restrict__ bar) {
  __shared__ float redp[2][128];
  __shared__ float cls[64], dds[64];
  __shared__ float yloc[268];
  __shared__ float red[256], red2[256];
  __shared__ float c0s;
  __shared__ unsigned tk;
  int t = threadIdx.x, bid = blockIdx.x;
  int b = ((bid & 7) << 1) | ((bid >> 3) & 1);
  int fq = bid >> 4;
  int f0 = fq * 256;
  {
    int k = t & 127, h = t >> 7;
    float s = 0.f;
    const float* pp = part + (size_t)h * 128 * 128 + k;
    for (int p = 0; p < 128; ++p) s += pp[(size_t)p * 128];
    redp[h][k] = s;
  }
  __syncthreads();
  if (t < 64) {
    float sum = redp[0][2 * t] + redp[1][2 * t];
    float sq  = redp[0][2 * t + 1] + redp[1][2 * t + 1];
    float m = sum * (1.f / 16384.f);
    float var = sq * (1.f / 16384.f) - m * m;     // biased, as jnp.var
    float inv = 1.f / sqrtf(var + 1e-5f);
    float g = bn1_g[t], be = bn1_b[t], lw = lc_W[t];
    cls[t] = lw * g * inv;
    dds[t] = lw * (be - m * inv * g);
  }
  __syncthreads();
  if (t == 0) {
    float s = 0.f;
    for (int n = 0; n < 64; ++n) s += dds[n];
    c0s = s + lc_b[0];
  }
  __syncthreads();
  float c0 = c0s;
  for (int idx = t; idx < 268; idx += 256) {
    int f = f0 - 6 + idx;
    float acc = 0.f;
    if (f >= 0 && f < 1024) {
      acc = c0;
      const float* col = h2 + (size_t)(b * 64) * 1024 + f;
      for (int n = 0; n < 64; ++n) acc += cls[n] * col[(size_t)n * 1024];
    }
    yloc[idx] = acc;
  }
  __syncthreads();
  float cw[13];
#pragma unroll
  for (int k = 0; k < 13; ++k) cw[k] = conv_W[k];
  float vv = conv_b[0];
#pragma unroll
  for (int k = 0; k < 13; ++k) vv += yloc[t + k] * cw[k];
  y2[b * 1024 + f0 + t] = vv;
  red[t] = vv; red2[t] = vv * vv;
  __syncthreads();
  for (int off = 128; off > 0; off >>= 1) {
    if (t < off) { red[t] += red[t + off]; red2[t] += red2[t + off]; }
    __syncthreads();
  }
  if (t == 0) {
    int dchunk = b * 4 + fq;
    bn2part[2 * dchunk] = red[0]; bn2part[2 * dchunk + 1] = red2[0];
  }

  // --- modulo terminal ticket: exactly one block per launch draws (tk&63)==63.
  //     Empirically safe (zeroed first-call ws; replay-stable data). ---
  __syncthreads();                                 // all block stores drained (vmcnt)
  if (t == 0) { __threadfence(); tk = atomicAdd(bar, 1u); }
  __syncthreads();
  if ((tk & 63u) != 63u) return;
  __threadfence();                                 // acquire: see all blocks' y2/bn2part

  {
    float S = 0.f, S2 = 0.f;
    for (int i = 0; i < 64; ++i) { S += bn2part[2 * i]; S2 += bn2part[2 * i + 1]; }
    float m2 = S * (1.f / 16384.f);
    float inv2 = 1.f / sqrtf(S2 * (1.f / 16384.f) - m2 * m2 + 1e-5f);
    float g2 = bn2_g[0] * inv2, be2 = bn2_b[0];
    int hb = t >> 4, seg = t & 15;
    const float4* yv = reinterpret_cast<const float4*>(&y2[hb * 1024 + seg * 64]);
    const float4* w0 = reinterpret_cast<const float4*>(&out_W[seg * 64]);
    const float4* w1 = reinterpret_cast<const float4*>(&out_W[1024 + seg * 64]);
    float a0 = 0.f, a1 = 0.f;
#pragma unroll 4
    for (int u = 0; u < 16; ++u) {
      float4 y4 = yv[u], cc0 = w0[u], cc1 = w1[u];
      float vx = fmaxf((y4.x - m2) * g2 + be2, 0.f);
      float vy = fmaxf((y4.y - m2) * g2 + be2, 0.f);
      float vz = fmaxf((y4.z - m2) * g2 + be2, 0.f);
      float vw = fmaxf((y4.w - m2) * g2 + be2, 0.f);
      a0 += vx * cc0.x + vy * cc0.y + vz * cc0.z + vw * cc0.w;
      a1 += vx * cc1.x + vy * cc1.y + vz * cc1.z + vw * cc1.w;
    }
    red[t] = a0; red2[t] = a1;                     // reuse reduction arrays
    __syncthreads();
    for (int off = 8; off > 0; off >>= 1) {
      if (seg < off) { red[t] += red[t + off]; red2[t] += red2[t + off]; }
      __syncthreads();
    }
    if (seg == 0) {
      float l0 = red[t] + out_b[0], l1 = red2[t] + out_b[1];
      float mx = fmaxf(l0, l1);
      float e0 = expf(l0 - mx), e1 = expf(l1 - mx);
      float inv = 1.f / (e0 + e1);
      dout[hb * 2 + 0] = e0 * inv;
      dout[hb * 2 + 1] = e1 * inv;
    }
  }
}

extern "C" void kernel_launch(void* const* d_in, const int* in_sizes, int n_in,
                              void* d_out, int out_size, void* d_ws, size_t ws_size,
                              hipStream_t stream) {
  (void)in_sizes; (void)n_in; (void)out_size; (void)ws_size;
  const float* x      = (const float*)d_in[0];
  const float* w      = (const float*)d_in[1];
  const float* gin_W  = (const float*)d_in[2];
  const float* gin_b  = (const float*)d_in[3];
  const float* bn1_g  = (const float*)d_in[4];
  const float* bn1_b  = (const float*)d_in[5];
  const float* lc_W   = (const float*)d_in[6];
  const float* lc_b   = (const float*)d_in[7];
  const float* conv_W = (const float*)d_in[8];
  const float* conv_b = (const float*)d_in[9];
  const float* bn2_g  = (const float*)d_in[10];
  const float* bn2_b  = (const float*)d_in[11];
  const float* out_W  = (const float*)d_in[12];
  const float* out_b  = (const float*)d_in[13];
  float* dout = (float*)d_out;

  char* ws = (char*)d_ws;
  float* spart   = (float*)ws;                                  // 4 MB
  float* h2      = (float*)(ws + (4u << 20));                   // 4 MB
  float* gpart   = (float*)(ws + (8u << 20));                   // 8 MB (2 K-slices)
  float* part    = (float*)(ws + (16u << 20));                  // 128 KB (256 x 128 f32)
  float* y2      = (float*)(ws + (16u << 20) + (128u << 10));   // 64 KB
  float* bn2part = (float*)(ws + (16u << 20) + (192u << 10));   // 128 f32
  unsigned* bar  = (unsigned*)(ws + (16u << 20) + (194u << 10)); // ticket counter (never reset)

  k1_spart_gemm<<<dim3(768), dim3(256), 0, stream>>>(x, w, gin_W, spart, gpart);
  k2_adj_h2    <<<dim3(256), dim3(256), 0, stream>>>(spart, gpart, gin_b, dout, h2, part);
  k3_y_head    <<<dim3(64),  dim3(256), 0, stream>>>(h2, part, lc_W, lc_b, bn1_g, bn1_b,
                                                     conv_W, conv_b, bn2_g, bn2_b, out_W, out_b,
                                                     y2, bn2part, dout, bar);
}

// Round 19
// 62.287 us; speedup vs baseline: 1.0129x; 1.0129x over previous
//
#include <hip/hip_runtime.h>
#include <hip/hip_bf16.h>

// EdgeLearnGNN: B=16, N=64, F=1024, K=13, C=2
// Round 18: k2 -> 512 threads (8 waves), per-thread work halved (adj reduce 2x4
// patch, h2 2 rows) -- the thread-parallelism lever from r17 applied to the other
// big kernel, in isolation (r11 bundled it with a bad GEMM move). k1 (r18 64x64
// XCD-local GEMM + spart), k3, ws layout: byte-identical. Budget: k1~16 k2~13
// k3~3 boundaries~6; if this is null, ~63us is the structural floor.
//   K1: 768 blocks: 512 GEMM g=x@W^T (64x64 x K512, XCD-local) | 256 spart+warm
//   K2: 256 blocks x 512 thr (b,ft): adj recompute + h2=(A+I)@g+gin_b + BN1 part
//   K3: 64 blocks: BN1 reduce + folded mix + conv13 + BN2 part + [mod-ticket: head]

typedef __attribute__((ext_vector_type(8))) __bf16 bf16x8;
typedef __attribute__((ext_vector_type(4))) float f32x4;

__device__ __forceinline__ unsigned short f2bf(float f) {
  union { float f; unsigned int u; } v; v.f = f;
  unsigned int r = v.u + 0x7FFFu + ((v.u >> 16) & 1u);   // RNE, finite values only
  return (unsigned short)(r >> 16);
}

// ---------------- K1: XCD-local GEMM (bid<512) + spart tiles (bid>=512) ----------------
__global__ __launch_bounds__(256) void k1_spart_gemm(
    const float* __restrict__ x, const float* __restrict__ w,
    const float* __restrict__ gin_W,
    float* __restrict__ spart, float* __restrict__ gpart) {
  __shared__ __align__(16) union {
    struct { float xt[64 * 68]; float wt[64]; } s;
    struct { unsigned short A[64 * 72]; unsigned short B[64 * 72]; } g;   // 18.4 KB
  } sm;
  int t = threadIdx.x, bid = blockIdx.x;

  if (bid >= 512) {
    // ----- pairwise weighted-L1 partial scores, tile (b, ft) + gin_W warm -----
    int sbid = bid - 512;
    int b = sbid >> 4, ft = sbid & 15, f0 = ft * 64;
    const float4* pf = reinterpret_cast<const float4*>(gin_W) + (size_t)sbid * 1024 + t;
    float4 pf0 = pf[0], pf1 = pf[256], pf2 = pf[512], pf3 = pf[768];
    for (int c = 0; c < 16; ++c) {
      int idx = c * 256 + t;
      int n = idx >> 6, f = idx & 63;
      sm.s.xt[n * 68 + f] = x[b * 65536 + n * 1024 + f0 + f];
    }
    if (t < 64) sm.s.wt[t] = w[f0 + t];
    __syncthreads();
    asm volatile("" :: "v"(pf0.x), "v"(pf1.x), "v"(pf2.x), "v"(pf3.x));  // keep loads live
    int i0 = (t >> 4) * 4, j0 = (t & 15) * 4;
    float acc[4][4];
#pragma unroll
    for (int ii = 0; ii < 4; ++ii)
#pragma unroll
      for (int jj = 0; jj < 4; ++jj) acc[ii][jj] = 0.f;
    for (int f = 0; f < 64; f += 4) {
      float4 wv = *reinterpret_cast<const float4*>(&sm.s.wt[f]);
      float4 av[4], bv[4];
#pragma unroll
      for (int ii = 0; ii < 4; ++ii) av[ii] = *reinterpret_cast<const float4*>(&sm.s.xt[(i0 + ii) * 68 + f]);
#pragma unroll
      for (int jj = 0; jj < 4; ++jj) bv[jj] = *reinterpret_cast<const float4*>(&sm.s.xt[(j0 + jj) * 68 + f]);
#pragma unroll
      for (int ii = 0; ii < 4; ++ii)
#pragma unroll
        for (int jj = 0; jj < 4; ++jj) {
          acc[ii][jj] += fabsf(av[ii].x - bv[jj].x) * wv.x
                       + fabsf(av[ii].y - bv[jj].y) * wv.y
                       + fabsf(av[ii].z - bv[jj].z) * wv.z
                       + fabsf(av[ii].w - bv[jj].w) * wv.w;
        }
    }
    float* out = spart + (size_t)sbid * 4096;
#pragma unroll
    for (int ii = 0; ii < 4; ++ii)
#pragma unroll
      for (int jj = 0; jj < 4; ++jj)
        out[(i0 + ii) * 64 + (j0 + jj)] = acc[ii][jj];
    return;
  }

  // ----- GEMM g = x @ W^T: 512 blocks, tile 64x64, K-slice 512, XCD regions -----
  int g = bid;
  int xcd = g & 7, idx = g >> 3;
  int lt = idx & 31, slice = idx >> 5;
  int tr = 4 * (xcd & 3) + (lt >> 3);      // 0..15 (M-tile of 64 rows)
  int tc = 8 * (xcd >> 2) + (lt & 7);      // 0..15 (N-tile of 64 cols)
  int k0 = slice * 512;
  int wave = t >> 6, lane = t & 63;
  int wr = wave * 16;                      // wave: 16 rows x 64 cols
  int lrow = lane & 15, kg = lane >> 4;
  f32x4 acc[4];
#pragma unroll
  for (int nj = 0; nj < 4; ++nj) acc[nj] = f32x4{0.f, 0.f, 0.f, 0.f};

  for (int chunk = 0; chunk < 8; ++chunk) {
    int kc = k0 + chunk * 64;
#pragma unroll
    for (int u = 0; u < 4; ++u) {            // A: 64 rows x 64 k
      int idx4 = u * 256 + t;
      int row = idx4 >> 4, kq = idx4 & 15;
      float4 va = *reinterpret_cast<const float4*>(&x[(size_t)(tr * 64 + row) * 1024 + kc + kq * 4]);
      ushort4 ua; ua.x = f2bf(va.x); ua.y = f2bf(va.y); ua.z = f2bf(va.z); ua.w = f2bf(va.w);
      *reinterpret_cast<ushort4*>(&sm.g.A[row * 72 + kq * 4]) = ua;
    }
#pragma unroll
    for (int u = 0; u < 4; ++u) {            // B: 64 rows x 64 k
      int idx4 = u * 256 + t;
      int row = idx4 >> 4, kq = idx4 & 15;
      float4 vb = *reinterpret_cast<const float4*>(&gin_W[(size_t)(tc * 64 + row) * 1024 + kc + kq * 4]);
      ushort4 ub; ub.x = f2bf(vb.x); ub.y = f2bf(vb.y); ub.z = f2bf(vb.z); ub.w = f2bf(vb.w);
      *reinterpret_cast<ushort4*>(&sm.g.B[row * 72 + kq * 4]) = ub;
    }
    __syncthreads();
#pragma unroll
    for (int ks = 0; ks < 2; ++ks) {
      bf16x8 a = *reinterpret_cast<const bf16x8*>(&sm.g.A[(wr + lrow) * 72 + ks * 32 + kg * 8]);
      bf16x8 bf_[4];
#pragma unroll
      for (int nj = 0; nj < 4; ++nj)
        bf_[nj] = *reinterpret_cast<const bf16x8*>(&sm.g.B[(nj * 16 + lrow) * 72 + ks * 32 + kg * 8]);
#pragma unroll
      for (int nj = 0; nj < 4; ++nj)
        acc[nj] = __builtin_amdgcn_mfma_f32_16x16x32_bf16(a, bf_[nj], acc[nj], 0, 0, 0);
    }
    __syncthreads();
  }
  float* gp = gpart + (size_t)slice * (1024u * 1024u);
#pragma unroll
  for (int nj = 0; nj < 4; ++nj) {
    int row = tr * 64 + wr + kg * 4;              // C/D: row = (lane>>4)*4 + reg
    int col = tc * 64 + nj * 16 + lrow;           // col = lane&15
#pragma unroll
    for (int r = 0; r < 4; ++r)
      gp[(size_t)(row + r) * 1024 + col] = acc[nj][r];
  }
}

// ---- K2: 512 threads. adj[b] recompute + h2 = (A+I)@g + gin_b + BN1 partials. ----
// XCD-swizzled: the 16 blocks of batch b share one XCD -> spart[b]+g[b] L2-hit.
// Thread owns: gt 2 rows; adj 2x4 patch; h2 2 rows x 4 cols.
__global__ __launch_bounds__(512) void k2_adj_h2(
    const float* __restrict__ spart, const float* __restrict__ gpart,
    const float* __restrict__ gin_b,
    float* __restrict__ dout, float* __restrict__ h2, float* __restrict__ part) {
  __shared__ float adjs[64 * 65];
  __shared__ float csum[32][64];
  __shared__ float cinv[64];
  __shared__ __align__(16) float gt[64 * 68];
  int t = threadIdx.x, bid = blockIdx.x;
  int xcd = bid & 7, local = bid >> 3;
  int b = (xcd << 1) | (local & 1);
  int ft = local >> 1;
  int f0 = ft * 64;
  // g tile: sum the 2 K-slice partials -> gt[64][68] (thread: 2 rows)
  {
    int i = t >> 4, fl = (t & 15) * 4;          // i in 0..31
#pragma unroll
    for (int c = 0; c < 2; ++c) {
      int row = c * 32 + i;
      const float* base = gpart + (size_t)(b * 64 + row) * 1024 + f0 + fl;
      float4 s0 = *reinterpret_cast<const float4*>(base);
      float4 s1 = *reinterpret_cast<const float4*>(base + (1u << 20));
      float4 g4;
      g4.x = s0.x + s1.x; g4.y = s0.y + s1.y;
      g4.z = s0.z + s1.z; g4.w = s0.w + s1.w;
      *reinterpret_cast<float4*>(&gt[row * 68 + fl]) = g4;
    }
  }
  // adj[b] from spart: thread owns rows tr2*2..+1 x cols tj*4..+3
  int tj = t & 15, tr2 = t >> 4;              // tr2 in 0..31
  float4 v4[2];
#pragma unroll
  for (int r = 0; r < 2; ++r) v4[r] = make_float4(0.f, 0.f, 0.f, 0.f);
  for (int ft2 = 0; ft2 < 16; ++ft2) {
    const float* p = spart + (size_t)(b * 16 + ft2) * 4096 + tj * 4;
#pragma unroll
    for (int r = 0; r < 2; ++r) {
      float4 s = *reinterpret_cast<const float4*>(&p[(tr2 * 2 + r) * 64]);
      v4[r].x += s.x; v4[r].y += s.y; v4[r].z += s.z; v4[r].w += s.w;
    }
  }
  float4 colsum = make_float4(0.f, 0.f, 0.f, 0.f);
#pragma unroll
  for (int r = 0; r < 2; ++r) {
    float4 e;
    e.x = expf(-fmaxf(v4[r].x, 0.f));
    e.y = expf(-fmaxf(v4[r].y, 0.f));
    e.z = expf(-fmaxf(v4[r].z, 0.f));
    e.w = expf(-fmaxf(v4[r].w, 0.f));
    int row = tr2 * 2 + r;
    adjs[row * 65 + tj * 4 + 0] = e.x;
    adjs[row * 65 + tj * 4 + 1] = e.y;
    adjs[row * 65 + tj * 4 + 2] = e.z;
    adjs[row * 65 + tj * 4 + 3] = e.w;
    colsum.x += e.x; colsum.y += e.y; colsum.z += e.z; colsum.w += e.w;
  }
  csum[tr2][tj * 4 + 0] = colsum.x;
  csum[tr2][tj * 4 + 1] = colsum.y;
  csum[tr2][tj * 4 + 2] = colsum.z;
  csum[tr2][tj * 4 + 3] = colsum.w;
  __syncthreads();
  if (t < 64) {
    float s = 0.f;
#pragma unroll
    for (int g2 = 0; g2 < 32; ++g2) s += csum[g2][t];
    cinv[t] = 1.f / s;
  }
  __syncthreads();
  float* doutAdj = dout + 32 + (size_t)b * 4096;
#pragma unroll
  for (int r = 0; r < 2; ++r) {
    int row = tr2 * 2 + r;
#pragma unroll
    for (int c = 0; c < 4; ++c) {
      int col = tj * 4 + c;
      float a = adjs[row * 65 + col] * cinv[col];
      adjs[row * 65 + col] = a;
      if (ft == 0) doutAdj[row * 64 + col] = a;
    }
  }
  __syncthreads();
  // h2 tile = gt (identity) + adj@gt + gin_b; 2 rows x 4 cols per thread
  int i0 = (t >> 4) * 2, fl = (t & 15) * 4;   // i0: 0..62 step 2
  float4 gbv = *reinterpret_cast<const float4*>(&gin_b[f0 + fl]);
  float4 acc4[2];
  acc4[0] = *reinterpret_cast<const float4*>(&gt[i0 * 68 + fl]);        // identity
  acc4[1] = *reinterpret_cast<const float4*>(&gt[(i0 + 1) * 68 + fl]);
  for (int j = 0; j < 64; ++j) {
    float4 gv = *reinterpret_cast<const float4*>(&gt[j * 68 + fl]);
    float a0 = adjs[i0 * 65 + j], a1 = adjs[(i0 + 1) * 65 + j];
    acc4[0].x += a0 * gv.x; acc4[0].y += a0 * gv.y; acc4[0].z += a0 * gv.z; acc4[0].w += a0 * gv.w;
    acc4[1].x += a1 * gv.x; acc4[1].y += a1 * gv.y; acc4[1].z += a1 * gv.z; acc4[1].w += a1 * gv.w;
  }
  float rs[2], rq[2];
#pragma unroll
  for (int ii = 0; ii < 2; ++ii) {
    acc4[ii].x += gbv.x; acc4[ii].y += gbv.y; acc4[ii].z += gbv.z; acc4[ii].w += gbv.w;
    *reinterpret_cast<float4*>(&h2[(size_t)(b * 64 + i0 + ii) * 1024 + f0 + fl]) = acc4[ii];
    rs[ii] = (acc4[ii].x + acc4[ii].y) + (acc4[ii].z + acc4[ii].w);
    rq[ii] = (acc4[ii].x * acc4[ii].x + acc4[ii].y * acc4[ii].y)
           + (acc4[ii].z * acc4[ii].z + acc4[ii].w * acc4[ii].w);
  }
#pragma unroll
  for (int m = 1; m < 16; m <<= 1) {
#pragma unroll
    for (int r = 0; r < 2; ++r) {
      rs[r] += __shfl_xor(rs[r], m, 64);
      rq[r] += __shfl_xor(rq[r], m, 64);
    }
  }
  if ((t & 15) == 0) {
    float* pp = part + (size_t)(b * 16 + ft) * 128;
#pragma unroll
    for (int r = 0; r < 2; ++r) {
      int n = i0 + r;
      pp[2 * n]     = rs[r];
      pp[2 * n + 1] = rq[r];
    }
  }
}

// ---- K3: 64 blocks (b, 256-f quarter). BN1 reduce + folded mix + conv13 +
//      BN2 partials; modulo terminal ticket -> unique residue-63 block runs the head. ----
__global__ __launch_bounds__(256) void k3_y_head(
    const float* __restrict__ h2, const float* __restrict__ part,
    const float* __restrict__ lc_W, const float* __restrict__ lc_b,
    const float* __restrict__ bn1_g, const float* __restrict__ bn1_b,
    const float* __restrict__ conv_W, const float* __restrict__ conv_b,
    const float* __restrict__ bn2_g, const float* __restrict__ bn2_b,
    const float* __restrict__ out_W, const float* __restrict__ out_b,
    float* __restrict__ y2, float* __restrict__ bn2part,
    float* __restrict__ dout, unsigned* __restrict__ bar) {
  __shared__ float redp[2][128];
  __shared__ float cls[64], dds[64];
  __shared__ float yloc[268];
  __shared__ float red[256], red2[256];
  __shared__ float c0s;
  __shared__ unsigned tk;
  int t = threadIdx.x, bid = blockIdx.x;
  int b = ((bid & 7) << 1) | ((bid >> 3) & 1);
  int fq = bid >> 4;
  int f0 = fq * 256;
  {
    int k = t & 127, h = t >> 7;
    float s = 0.f;
    const float* pp = part + (size_t)h * 128 * 128 + k;
    for (int p = 0; p < 128; ++p) s += pp[(size_t)p * 128];
    redp[h][k] = s;
  }
  __syncthreads();
  if (t < 64) {
    float sum = redp[0][2 * t] + redp[1][2 * t];
    float sq  = redp[0][2 * t + 1] + redp[1][2 * t + 1];
    float m = sum * (1.f / 16384.f);
    float var = sq * (1.f / 16384.f) - m * m;     // biased, as jnp.var
    float inv = 1.f / sqrtf(var + 1e-5f);
    float g = bn1_g[t], be = bn1_b[t], lw = lc_W[t];
    cls[t] = lw * g * inv;
    dds[t] = lw * (be - m * inv * g);
  }
  __syncthreads();
  if (t == 0) {
    float s = 0.f;
    for (int n = 0; n < 64; ++n) s += dds[n];
    c0s = s + lc_b[0];
  }
  __syncthreads();
  float c0 = c0s;
  for (int idx = t; idx < 268; idx += 256) {
    int f = f0 - 6 + idx;
    float acc = 0.f;
    if (f >= 0 && f < 1024) {
      acc = c0;
      const float* col = h2 + (size_t)(b * 64) * 1024 + f;
      for (int n = 0; n < 64; ++n) acc += cls[n] * col[(size_t)n * 1024];
    }
    yloc[idx] = acc;
  }
  __syncthreads();
  float cw[13];
#pragma unroll
  for (int k = 0; k < 13; ++k) cw[k] = conv_W[k];
  float vv = conv_b[0];
#pragma unroll
  for (int k = 0; k < 13; ++k) vv += yloc[t + k] * cw[k];
  y2[b * 1024 + f0 + t] = vv;
  red[t] = vv; red2[t] = vv * vv;
  __syncthreads();
  for (int off = 128; off > 0; off >>= 1) {
    if (t < off) { red[t] += red[t + off]; red2[t] += red2[t + off]; }
    __syncthreads();
  }
  if (t == 0) {
    int dchunk = b * 4 + fq;
    bn2part[2 * dchunk] = red[0]; bn2part[2 * dchunk + 1] = red2[0];
  }

  // --- modulo terminal ticket: exactly one block per launch draws (tk&63)==63.
  //     Empirically safe (zeroed first-call ws; replay-stable data). ---
  __syncthreads();                                 // all block stores drained (vmcnt)
  if (t == 0) { __threadfence(); tk = atomicAdd(bar, 1u); }
  __syncthreads();
  if ((tk & 63u) != 63u) return;
  __threadfence();                                 // acquire: see all blocks' y2/bn2part

  {
    float S = 0.f, S2 = 0.f;
    for (int i = 0; i < 64; ++i) { S += bn2part[2 * i]; S2 += bn2part[2 * i + 1]; }
    float m2 = S * (1.f / 16384.f);
    float inv2 = 1.f / sqrtf(S2 * (1.f / 16384.f) - m2 * m2 + 1e-5f);
    float g2 = bn2_g[0] * inv2, be2 = bn2_b[0];
    int hb = t >> 4, seg = t & 15;
    const float4* yv = reinterpret_cast<const float4*>(&y2[hb * 1024 + seg * 64]);
    const float4* w0 = reinterpret_cast<const float4*>(&out_W[seg * 64]);
    const float4* w1 = reinterpret_cast<const float4*>(&out_W[1024 + seg * 64]);
    float a0 = 0.f, a1 = 0.f;
#pragma unroll 4
    for (int u = 0; u < 16; ++u) {
      float4 y4 = yv[u], cc0 = w0[u], cc1 = w1[u];
      float vx = fmaxf((y4.x - m2) * g2 + be2, 0.f);
      float vy = fmaxf((y4.y - m2) * g2 + be2, 0.f);
      float vz = fmaxf((y4.z - m2) * g2 + be2, 0.f);
      float vw = fmaxf((y4.w - m2) * g2 + be2, 0.f);
      a0 += vx * cc0.x + vy * cc0.y + vz * cc0.z + vw * cc0.w;
      a1 += vx * cc1.x + vy * cc1.y + vz * cc1.z + vw * cc1.w;
    }
    red[t] = a0; red2[t] = a1;                     // reuse reduction arrays
    __syncthreads();
    for (int off = 8; off > 0; off >>= 1) {
      if (seg < off) { red[t] += red[t + off]; red2[t] += red2[t + off]; }
      __syncthreads();
    }
    if (seg == 0) {
      float l0 = red[t] + out_b[0], l1 = red2[t] + out_b[1];
      float mx = fmaxf(l0, l1);
      float e0 = expf(l0 - mx), e1 = expf(l1 - mx);
      float inv = 1.f / (e0 + e1);
      dout[hb * 2 + 0] = e0 * inv;
      dout[hb * 2 + 1] = e1 * inv;
    }
  }
}

extern "C" void kernel_launch(void* const* d_in, const int* in_sizes, int n_in,
                              void* d_out, int out_size, void* d_ws, size_t ws_size,
                              hipStream_t stream) {
  (void)in_sizes; (void)n_in; (void)out_size; (void)ws_size;
  const float* x      = (const float*)d_in[0];
  const float* w      = (const float*)d_in[1];
  const float* gin_W  = (const float*)d_in[2];
  const float* gin_b  = (const float*)d_in[3];
  const float* bn1_g  = (const float*)d_in[4];
  const float* bn1_b  = (const float*)d_in[5];
  const float* lc_W   = (const float*)d_in[6];
  const float* lc_b   = (const float*)d_in[7];
  const float* conv_W = (const float*)d_in[8];
  const float* conv_b = (const float*)d_in[9];
  const float* bn2_g  = (const float*)d_in[10];
  const float* bn2_b  = (const float*)d_in[11];
  const float* out_W  = (const float*)d_in[12];
  const float* out_b  = (const float*)d_in[13];
  float* dout = (float*)d_out;

  char* ws = (char*)d_ws;
  float* spart   = (float*)ws;                                  // 4 MB
  float* h2      = (float*)(ws + (4u << 20));                   // 4 MB
  float* gpart   = (float*)(ws + (8u << 20));                   // 8 MB (2 K-slices)
  float* part    = (float*)(ws + (16u << 20));                  // 128 KB (256 x 128 f32)
  float* y2      = (float*)(ws + (16u << 20) + (128u << 10));   // 64 KB
  float* bn2part = (float*)(ws + (16u << 20) + (192u << 10));   // 128 f32
  unsigned* bar  = (unsigned*)(ws + (16u << 20) + (194u << 10)); // ticket counter (never reset)

  k1_spart_gemm<<<dim3(768), dim3(256), 0, stream>>>(x, w, gin_W, spart, gpart);
  k2_adj_h2    <<<dim3(256), dim3(512), 0, stream>>>(spart, gpart, gin_b, dout, h2, part);
  k3_y_head    <<<dim3(64),  dim3(256), 0, stream>>>(h2, part, lc_W, lc_b, bn1_g, bn1_b,
                                                     conv_W, conv_b, bn2_g, bn2_b, out_W, out_b,
                                                     y2, bn2part, dout, bar);
}